// Round 14
// baseline (280.380 us; speedup 1.0000x reference)
//
#include <hip/hip_runtime.h>
#include <math.h>

typedef unsigned short u16;
typedef unsigned int u32;
typedef __bf16 bf16x8 __attribute__((ext_vector_type(8)));
typedef unsigned short us8 __attribute__((ext_vector_type(8)));
typedef unsigned short us4 __attribute__((ext_vector_type(4)));
typedef float f32x4 __attribute__((ext_vector_type(4)));

#define DEV __device__ __forceinline__

DEV float fast_exp2(float x) { return __builtin_amdgcn_exp2f(x); }

DEV u16 f2bf(float f) {
  __bf16 h = (__bf16)f;
  return __builtin_bit_cast(u16, h);
}
DEV float bf2f(u16 h) { return __builtin_bit_cast(float, (u32)h << 16); }

DEV bf16x8 ld_bf8(const u16* p) { return __builtin_bit_cast(bf16x8, *(const us8*)p); }

DEV void gload_lds16(const u16* g, u16* l) {
  __builtin_amdgcn_global_load_lds((const __attribute__((address_space(1))) void*)g,
                                   (__attribute__((address_space(3))) void*)l, 16, 0, 0);
}

DEV f32x4 mfma16(bf16x8 a, bf16x8 b, f32x4 c) {
  return __builtin_amdgcn_mfma_f32_16x16x32_bf16(a, b, c, 0, 0, 0);
}

// tanh-form GELU, exp2-based
DEV float fast_gelu(float u) {
  const float e = fast_exp2(-u * (2.3022048f + 0.10294343f * u * u));
  return u / (1.f + e);
}

#define BAR __builtin_amdgcn_s_barrier()
#define LGK asm volatile("s_waitcnt lgkmcnt(0)" ::: "memory")
#define VM4 asm volatile("s_waitcnt vmcnt(4)" ::: "memory")
#define VM0 asm volatile("s_waitcnt vmcnt(0)" ::: "memory")

// ---------------- prep kernels ----------------

__global__ void conv_bf16_kernel(const float* __restrict__ in, u16* __restrict__ out, int n4) {
  const int stride = gridDim.x * blockDim.x;
  for (int i = blockIdx.x * blockDim.x + threadIdx.x; i < n4; i += stride) {
    float4 v = ((const float4*)in)[i];
    us4 h; h[0] = f2bf(v.x); h[1] = f2bf(v.y); h[2] = f2bf(v.z); h[3] = f2bf(v.w);
    ((us4*)out)[i] = h;
  }
}

// in: K x N f32 (row-major) -> out: N x K bf16 (B^T), times scale.
// P=0 plain; P=1 permute OUT row c' = ((c&15)<<6)|(c>>4); P=2 gather IN row src=((r&63)<<4)|(r>>6)
template <int P>
__global__ __launch_bounds__(256) void transpose_bf16_kernel(
    const float* __restrict__ in, u16* __restrict__ out, int K, int N, float scale) {
  __shared__ float tile[32][33];
  const int nbk = K >> 5;
  const int bk = blockIdx.x % nbk, bn = blockIdx.x / nbk;
  const int r0 = bk << 5, c0 = bn << 5;
  const int t = threadIdx.x;
  {
    const int r = t >> 3, c4 = (t & 7) << 2;
    int sr = r0 + r;
    if constexpr (P == 2) sr = ((sr & 63) << 4) | (sr >> 6);
    const float4 v = *(const float4*)(in + (size_t)sr * N + c0 + c4);
    tile[r][c4] = v.x; tile[r][c4 + 1] = v.y; tile[r][c4 + 2] = v.z; tile[r][c4 + 3] = v.w;
  }
  __syncthreads();
  {
    const int oc = t >> 3, r4 = (t & 7) << 2;
    int orow = c0 + oc;
    if constexpr (P == 1) orow = ((orow & 15) << 6) | (orow >> 4);
    us4 h;
#pragma unroll
    for (int j = 0; j < 4; j++) h[j] = f2bf(tile[r4 + j][oc] * scale);
    *(us4*)(out + (size_t)orow * K + r0 + r4) = h;
  }
}

// k half of qkP partials (summed) -> kth [b][n][d][l] and ksum [b][n][l][d]
__global__ __launch_bounds__(256) void khead_transpose(
    const u16* __restrict__ qkP, u16* __restrict__ kth, u16* __restrict__ ksum) {
  __shared__ u16 tT[64 * 64];
  char* base = (char*)tT;
  const size_t PS = (size_t)4096 * 2048;  // partial stride
  const int t = threadIdx.x;
  const int bid = blockIdx.x;
  const int lt = bid & 31, n = (bid >> 5) & 15, b = bid >> 9;
#pragma unroll
  for (int rr = 0; rr < 2; rr++) {
    const int l = rr * 32 + (t >> 3);
    const int d0 = (t & 7) * 8;
    const size_t idx = ((size_t)(b * 2048 + lt * 64 + l)) * 2048 + 1024 + n * 64 + d0;
    us8 va = *(const us8*)(qkP + idx);
    us8 vb = *(const us8*)(qkP + PS + idx);
    us8 sm;
#pragma unroll
    for (int j = 0; j < 8; j++) sm[j] = f2bf(bf2f(va[j]) + bf2f(vb[j]));
    *(us8*)(ksum + (((size_t)(b * 16 + n) * 2048 + lt * 64 + l)) * 64 + d0) = sm;
#pragma unroll
    for (int j = 0; j < 8; j++) {
      const int d = d0 + j;
      *(u16*)(base + d * 128 + ((2 * l) ^ (16 * (d >> 3)))) = sm[j];
    }
  }
  __syncthreads();
  const int w = t >> 6, lane = t & 63;
#pragma unroll
  for (int rr = 0; rr < 2; rr++) {
    const int d = rr * 32 + w * 8 + (lane >> 3);
    const int l = (lane & 7) * 8;
    us8 v = *(const us8*)(base + d * 128 + ((2 * l) ^ (16 * (d >> 3))));
    *(us8*)(kth + ((size_t)((b * 16 + n) * 64 + d)) * 2048 + lt * 64 + l) = v;
  }
}

// ---------------- 4-phase 256x256 GEMM ----------------
// Main loop identical to R13 (verified). Change: AL/BL merged into one SH array
// (same offsets), and the epilogue now routes C through SH: scalar bf16 writes
// to a [256][256] LDS tile (col XOR ((row>>2)&3)<<4), then 16B coalesced global
// stores (128 scalar stores/thread -> 16 us8 stores/thread). vmcnt(0)+BAR
// before reuse drains the tail prefetch that still targets SH.
// MODE 0: ob = gelu(acc+bias) bf16 ; MODE 1: ob[ks*M*N+.] = acc bf16 partial
template <int MODE, int KS>
__global__ __launch_bounds__(512, 2) void gemm256(
    const u16* __restrict__ A, const u16* __restrict__ BT,
    int M, int N, int K,
    u16* __restrict__ ob, const float* __restrict__ bias) {
  __shared__ u16 SH[65536];  // loop: A = SH[0..32767], B = SH[32768..]; epilogue: [256][256]
  const int t = threadIdx.x;
  const int lane = t & 63, wid = t >> 6;
  const int lr = lane & 15, lg = lane >> 4;
  const int wm = wid >> 2, wn = wid & 3;
  const int nbm = M >> 8, nbn = N >> 8;
  const int nblk = nbm * nbn * KS;
  int bid = blockIdx.x;
  bid = (bid & 7) * (nblk >> 3) + (bid >> 3);
  int ks = 0;
  if constexpr (KS > 1) { ks = bid % KS; bid /= KS; }
  const int bm = bid % nbm, bn = bid / nbm;
  const int m0 = bm << 8, n0 = bn << 8;
  const int KB = K / KS;
  const int NT = KB >> 6;
  const u16* Ag = A + (size_t)m0 * K + ks * KB;
  const u16* Bg = BT + (size_t)n0 * K + ks * KB;
  const int sseg = (t & 7) ^ ((t >> 3) & 7);
  const int akey = lr & 7;

  auto stgA = [&](int buf, int h, int kt) {
    const u16* s = Ag + (size_t)(h * 128 + (t >> 3)) * K + kt * 64 + sseg * 8;
    u16* d = &SH[buf * 16384 + h * 8192];
    gload_lds16(s, d + t * 8);
    gload_lds16(s + (size_t)64 * K, d + 4096 + t * 8);
  };
  auto stgB = [&](int buf, int h, int kt) {
    const u16* s = Bg + (size_t)(h * 128 + (t >> 3)) * K + kt * 64 + sseg * 8;
    u16* d = &SH[32768 + buf * 16384 + h * 8192];
    gload_lds16(s, d + t * 8);
    gload_lds16(s + (size_t)64 * K, d + 4096 + t * 8);
  };

#define RDA(DST, BUF, IB)                                                      \
  _Pragma("unroll") for (int i4 = 0; i4 < 4; i4++)                             \
  _Pragma("unroll") for (int kk = 0; kk < 2; kk++)                             \
    DST[i4][kk] = ld_bf8(&SH[(BUF) * 16384 + wm * 8192 +                       \
                             ((IB + i4) * 16 + lr) * 64 +                      \
                             ((kk * 4 + lg) ^ akey) * 8]);
#define RDB(DST, BUF, JB)                                                      \
  _Pragma("unroll") for (int j2 = 0; j2 < 2; j2++)                             \
  _Pragma("unroll") for (int kk = 0; kk < 2; kk++)                             \
    DST[j2][kk] = ld_bf8(&SH[32768 + (BUF) * 16384 + (wn >> 1) * 8192 +        \
                             ((wn & 1) * 64 + (JB + j2) * 16 + lr) * 64 +      \
                             ((kk * 4 + lg) ^ akey) * 8]);
#define QUAD(AF, BF, IB, JB)                                                   \
  __builtin_amdgcn_s_setprio(1);                                               \
  _Pragma("unroll") for (int i4 = 0; i4 < 4; i4++)                             \
  _Pragma("unroll") for (int j2 = 0; j2 < 2; j2++)                             \
  _Pragma("unroll") for (int kk = 0; kk < 2; kk++)                             \
    acc[IB + i4][JB + j2] = mfma16(AF[i4][kk], BF[j2][kk], acc[IB + i4][JB + j2]); \
  __builtin_amdgcn_s_setprio(0);

  f32x4 acc[8][4];
#pragma unroll
  for (int i = 0; i < 8; i++)
#pragma unroll
    for (int j = 0; j < 4; j++) acc[i][j] = (f32x4){0.f, 0.f, 0.f, 0.f};
  bf16x8 a0[4][2], a1[4][2], b0[2][2], b1[2][2];

  stgA(0, 0, 0); stgA(0, 1, 0); stgB(0, 0, 0); stgB(0, 1, 0);
  stgA(1, 0, 1); stgA(1, 1, 1);
  VM4;
  BAR;

  const int NI = NT >> 1;
  for (int it = 0; it < NI; ++it) {
    const int kt1 = 2 * it + 1;
    const int ktA = (2 * it + 2 < NT) ? 2 * it + 2 : NT - 1;
    const int ktB = (2 * it + 3 < NT) ? 2 * it + 3 : NT - 1;
    // F1 (tile X, quadrants 1+2)
    RDA(a0, 0, 0); RDB(b0, 0, 0); RDA(a1, 0, 4); stgB(1, 0, kt1); stgB(1, 1, kt1);
    BAR; QUAD(a0, b0, 0, 0); QUAD(a1, b0, 4, 0); LGK; BAR;
    // F2 (tile X, quadrants 3+4)
    RDB(b1, 0, 2); stgA(0, 0, ktA); stgA(0, 1, ktA);
    BAR; QUAD(a1, b1, 4, 2); QUAD(a0, b1, 0, 2); LGK; VM4; BAR;
    // F3 (tile X+1, quadrants 1+2)
    RDA(a0, 1, 0); RDB(b0, 1, 0); RDA(a1, 1, 4); stgB(0, 0, ktA); stgB(0, 1, ktA);
    BAR; QUAD(a0, b0, 0, 0); QUAD(a1, b0, 4, 0); LGK; BAR;
    // F4 (tile X+1, quadrants 3+4)
    RDB(b1, 1, 2); stgA(1, 0, ktB); stgA(1, 1, ktB);
    BAR; QUAD(a1, b1, 4, 2); QUAD(a0, b1, 0, 2); LGK; VM4; BAR;
  }
#undef RDA
#undef RDB
#undef QUAD

  // ---- epilogue via LDS transpose ----
  VM0;  // drain tail prefetch still targeting SH
  BAR;
#pragma unroll
  for (int i = 0; i < 8; i++) {
    const int rloc = wm * 128 + i * 16 + lg * 4;
#pragma unroll
    for (int j = 0; j < 4; j++) {
      const int cloc = wn * 64 + j * 16 + lr;
      float bv = 0.f;
      if constexpr (MODE == 0) bv = bias[n0 + cloc];
#pragma unroll
      for (int q = 0; q < 4; q++) {
        float v = acc[i][j][q];
        if constexpr (MODE == 0) v = fast_gelu(v + bv);
        const int rr = rloc + q;
        SH[rr * 256 + (cloc ^ (((rr >> 2) & 3) << 4))] = f2bf(v);
      }
    }
  }
  BAR;
  {
    const int row = t >> 1, ch = (t & 1) * 128;
    const int key = ((row >> 2) & 3) << 4;
    u16* dst = (MODE == 1 ? ob + (size_t)ks * M * N : ob) + (size_t)(m0 + row) * N + n0 + ch;
#pragma unroll
    for (int cc = 0; cc < 16; cc++) {
      us8 vv = *(const us8*)&SH[row * 256 + ((ch + cc * 8) ^ key)];
      *(us8*)(dst + cc * 8) = vv;
    }
  }
}

// ---------------- attention (KV-split=2, no-max softmax, MFMA-ones denominator) ----------------
__global__ __launch_bounds__(256, 4) void attn_kernel(
    const u16* __restrict__ qkP, const u16* __restrict__ ksum,
    const u16* __restrict__ kth, u16* __restrict__ op, float* __restrict__ stat) {
  __shared__ u16 KsB[2][4096];
  __shared__ u16 KtsB[2][4096];
  __shared__ u16 Plds[4][1024];
  const size_t PS = (size_t)4096 * 2048;
  const int t = threadIdx.x, w = t >> 6, lane = t & 63;
  const int lr = lane & 15, lg = lane >> 4;
  int bid = blockIdx.x;
  bid = (bid & 7) * 128 + (bid >> 3);
  const int kv = bid & 1, qb = (bid >> 1) & 15, hn = (bid >> 5) & 15, b = bid >> 9;
  const int lw = qb * 128 + w * 32;
  const int m00 = kv * 1024;
  const u16* ksrc = ksum + ((size_t)(b * 16 + hn)) * 2048 * 64;
  const u16* ktb = kth + ((size_t)(b * 16 + hn)) * 64 * 2048;
  char* pb = (char*)&Plds[w][0];
  const int swz = (lr & 7) << 4;

#define STAGE_KV(buf, m0s)                                                    \
  {                                                                           \
    _Pragma("unroll") for (int i_ = 0; i_ < 2; i_++) {                        \
      const int s_ = t + 256 * i_;                                            \
      const int row_ = s_ >> 3;                                               \
      const int c_ = (s_ & 7) ^ (row_ & 7);                                   \
      gload_lds16(ksrc + (size_t)((m0s) + row_) * 64 + c_ * 8,                \
                  &KsB[buf][s_ * 8]);                                         \
      gload_lds16(ktb + (size_t)row_ * 2048 + (m0s) + c_ * 8,                 \
                  &KtsB[buf][s_ * 8]);                                        \
    }                                                                         \
  }

  bf16x8 qf[2][2];
#pragma unroll
  for (int f = 0; f < 2; f++)
#pragma unroll
    for (int kk = 0; kk < 2; kk++) {
      const size_t qi = (size_t)(b * 2048 + lw + 16 * f + lr) * 2048 + hn * 64 +
                        kk * 32 + lg * 8;
      us8 qa = *(const us8*)(qkP + qi);
      us8 qb2 = *(const us8*)(qkP + PS + qi);
      us8 qs;
#pragma unroll
      for (int j = 0; j < 8; j++) qs[j] = f2bf(bf2f(qa[j]) + bf2f(qb2[j]));
      qf[f][kk] = __builtin_bit_cast(bf16x8, qs);
    }

  us8 ou;
#pragma unroll
  for (int j = 0; j < 8; j++) ou[j] = 0x3f80;  // bf16 1.0
  const bf16x8 ones = __builtin_bit_cast(bf16x8, ou);

  f32x4 ol[2];
  f32x4 o[2][4];
#pragma unroll
  for (int f = 0; f < 2; f++) {
    ol[f] = (f32x4){0.f, 0.f, 0.f, 0.f};
#pragma unroll
    for (int dj = 0; dj < 4; dj++) o[f][dj] = (f32x4){0.f, 0.f, 0.f, 0.f};
  }

  STAGE_KV(0, m00);
  __syncthreads();

  for (int it = 0; it < 16; ++it) {
    const int buf = it & 1;
    if (it < 15) STAGE_KV(buf ^ 1, m00 + (it + 1) * 64);

    f32x4 sc[2][4];
#pragma unroll
    for (int f = 0; f < 2; f++)
#pragma unroll
      for (int mj = 0; mj < 4; mj++) sc[f][mj] = (f32x4){0.f, 0.f, 0.f, 0.f};
    __builtin_amdgcn_s_setprio(1);
#pragma unroll
    for (int mj = 0; mj < 4; mj++) {
      const int krow = 16 * mj + lr;
      bf16x8 kf0 = ld_bf8(&KsB[buf][krow * 64 + ((lg ^ (krow & 7)) << 3)]);
      bf16x8 kf1 = ld_bf8(&KsB[buf][krow * 64 + (((4 + lg) ^ (krow & 7)) << 3)]);
#pragma unroll
      for (int f = 0; f < 2; f++) {
        sc[f][mj] = mfma16(kf0, qf[f][0], sc[f][mj]);
        sc[f][mj] = mfma16(kf1, qf[f][1], sc[f][mj]);
      }
    }
    __builtin_amdgcn_s_setprio(0);

    bf16x8 pa[2][2];
#pragma unroll
    for (int f = 0; f < 2; f++) {
#pragma unroll
      for (int mj = 0; mj < 4; mj++) {
        float p0 = fast_exp2(sc[f][mj][0]);
        float p1 = fast_exp2(sc[f][mj][1]);
        float p2 = fast_exp2(sc[f][mj][2]);
        float p3 = fast_exp2(sc[f][mj][3]);
        u32 w0 = (u32)f2bf(p0) | ((u32)f2bf(p1) << 16);
        u32 w1 = (u32)f2bf(p2) | ((u32)f2bf(p3) << 16);
        *(uint2*)(pb + ((lr * 128 + mj * 32 + lg * 8) ^ swz)) = make_uint2(w0, w1);
      }
#pragma unroll
      for (int kk = 0; kk < 2; kk++)
        pa[f][kk] = __builtin_bit_cast(
            bf16x8, *(const us8*)(pb + ((lr * 128 + kk * 64 + lg * 16) ^ swz)));
      ol[f] = mfma16(pa[f][0], ones, ol[f]);
      ol[f] = mfma16(pa[f][1], ones, ol[f]);
    }

    __builtin_amdgcn_s_setprio(1);
#pragma unroll
    for (int dj = 0; dj < 4; dj++) {
      const int vrow = dj * 16 + lr;
      bf16x8 v0 = ld_bf8(&KtsB[buf][vrow * 64 + ((lg ^ (vrow & 7)) << 3)]);
      bf16x8 v1 = ld_bf8(&KtsB[buf][vrow * 64 + (((4 + lg) ^ (vrow & 7)) << 3)]);
#pragma unroll
      for (int f = 0; f < 2; f++) {
        o[f][dj] = mfma16(pa[f][0], v0, o[f][dj]);
        o[f][dj] = mfma16(pa[f][1], v1, o[f][dj]);
      }
    }
    __builtin_amdgcn_s_setprio(0);
    __syncthreads();
  }
#undef STAGE_KV

  u16* ob = op + (size_t)kv * 4096 * 1024;
#pragma unroll
  for (int f = 0; f < 2; f++) {
#pragma unroll
    for (int q = 0; q < 4; q++) {
      const int ll = lw + 16 * f + 4 * lg + q;
#pragma unroll
      for (int dj = 0; dj < 4; dj++) {
        ob[((size_t)(b * 2048 + ll)) * 1024 + hn * 64 + dj * 16 + lr] = f2bf(o[f][dj][q]);
      }
    }
    if (lr == 0) {
      const int sb = (b * 16 + hn) * 2048 + lw + 16 * f + 4 * lg;
#pragma unroll
      for (int q = 0; q < 4; q++) stat[kv * 65536 + sb + q] = ol[f][q];
    }
  }
}

// combine: ctx = (o0 + o1) / (l0 + l1)
__global__ __launch_bounds__(256) void attn_combine(
    const u16* __restrict__ op, const float* __restrict__ stat, u16* __restrict__ ctxh) {
  const int row = blockIdx.x, t = threadIdx.x;
  const int hn = t >> 4;
  const int b = row >> 11, l = row & 2047;
  const int sidx = (b * 16 + hn) * 2048 + l;
  const float inv = 1.f / (stat[sidx] + stat[65536 + sidx]);
  const us4 a = *(const us4*)(op + (size_t)row * 1024 + t * 4);
  const us4 c = *(const us4*)(op + (size_t)(4096 + row) * 1024 + t * 4);
  us4 h;
#pragma unroll
  for (int j = 0; j < 4; j++) h[j] = f2bf((bf2f(a[j]) + bf2f(c[j])) * inv);
  *(us4*)(ctxh + (size_t)row * 1024 + t * 4) = h;
}

// ---------------- layernorm ----------------
// ln1: 4 bf16 wo-partials + f32 x residual -> LN -> bf16 out
__global__ __launch_bounds__(256) void ln1_kernel(
    const u16* __restrict__ p, size_t pstride, const float* __restrict__ xres,
    const float* __restrict__ gamma, const float* __restrict__ beta,
    u16* __restrict__ o16) {
  __shared__ float red[8];
  const int row = blockIdx.x, t = threadIdx.x;
  float4 v = ((const float4*)(xres + (size_t)row * 1024))[t];
#pragma unroll
  for (int k = 0; k < 4; k++) {
    const us4 pv = *(const us4*)(p + (size_t)k * pstride + (size_t)row * 1024 + t * 4);
    v.x += bf2f(pv[0]); v.y += bf2f(pv[1]); v.z += bf2f(pv[2]); v.w += bf2f(pv[3]);
  }
  float s = v.x + v.y + v.z + v.w;
  float ss = v.x * v.x + v.y * v.y + v.z * v.z + v.w * v.w;
#pragma unroll
  for (int off = 1; off < 64; off <<= 1) { s += __shfl_xor(s, off); ss += __shfl_xor(ss, off); }
  if ((t & 63) == 0) { red[t >> 6] = s; red[4 + (t >> 6)] = ss; }
  __syncthreads();
  const float st = red[0] + red[1] + red[2] + red[3];
  const float sst = red[4] + red[5] + red[6] + red[7];
  const float mean = st * (1.f / 1024.f);
  const float var = sst * (1.f / 1024.f) - mean * mean;
  const float rs = rsqrtf(var + 1e-5f);
  const float4 gv = ((const float4*)gamma)[t];
  const float4 bv = ((const float4*)beta)[t];
  us4 h;
  h[0] = f2bf((v.x - mean) * rs * gv.x + bv.x);
  h[1] = f2bf((v.y - mean) * rs * gv.y + bv.y);
  h[2] = f2bf((v.z - mean) * rs * gv.z + bv.z);
  h[3] = f2bf((v.w - mean) * rs * gv.w + bv.w);
  *(us4*)(o16 + (size_t)row * 1024 + t * 4) = h;
}

// ln2: 4 bf16 partials + bf16 residual + bias -> LN -> f32 out
__global__ __launch_bounds__(256) void ln2_kernel(
    const u16* __restrict__ p, size_t pstride,
    const u16* __restrict__ resb, const float* __restrict__ bias,
    const float* __restrict__ gamma, const float* __restrict__ beta,
    float* __restrict__ o32) {
  __shared__ float red[8];
  const int row = blockIdx.x, t = threadIdx.x;
  float4 v;
  {
    const float4 vb = ((const float4*)bias)[t];
    const us4 rb = *(const us4*)(resb + (size_t)row * 1024 + t * 4);
    v.x = bf2f(rb[0]) + vb.x;
    v.y = bf2f(rb[1]) + vb.y;
    v.z = bf2f(rb[2]) + vb.z;
    v.w = bf2f(rb[3]) + vb.w;
  }
#pragma unroll
  for (int k = 0; k < 4; k++) {
    const us4 pv = *(const us4*)(p + (size_t)k * pstride + (size_t)row * 1024 + t * 4);
    v.x += bf2f(pv[0]); v.y += bf2f(pv[1]); v.z += bf2f(pv[2]); v.w += bf2f(pv[3]);
  }
  float s = v.x + v.y + v.z + v.w;
  float ss = v.x * v.x + v.y * v.y + v.z * v.z + v.w * v.w;
#pragma unroll
  for (int off = 1; off < 64; off <<= 1) { s += __shfl_xor(s, off); ss += __shfl_xor(ss, off); }
  if ((t & 63) == 0) { red[t >> 6] = s; red[4 + (t >> 6)] = ss; }
  __syncthreads();
  const float st = red[0] + red[1] + red[2] + red[3];
  const float sst = red[4] + red[5] + red[6] + red[7];
  const float mean = st * (1.f / 1024.f);
  const float var = sst * (1.f / 1024.f) - mean * mean;
  const float rs = rsqrtf(var + 1e-5f);
  const float4 gv = ((const float4*)gamma)[t];
  const float4 bv = ((const float4*)beta)[t];
  float4 ov;
  ov.x = (v.x - mean) * rs * gv.x + bv.x;
  ov.y = (v.y - mean) * rs * gv.y + bv.y;
  ov.z = (v.z - mean) * rs * gv.z + bv.z;
  ov.w = (v.w - mean) * rs * gv.w + bv.w;
  ((float4*)(o32 + (size_t)row * 1024))[t] = ov;
}

// ---------------- launch ----------------
extern "C" void kernel_launch(void* const* d_in, const int* in_sizes, int n_in,
                              void* d_out, int out_size, void* d_ws, size_t ws_size,
                              hipStream_t stream) {
  const float* x   = (const float*)d_in[0];
  const float* wq  = (const float*)d_in[1];
  const float* wk  = (const float*)d_in[2];
  const float* wo  = (const float*)d_in[3];
  const float* g1  = (const float*)d_in[4];
  const float* b1  = (const float*)d_in[5];
  const float* w1  = (const float*)d_in[6];
  const float* bb1 = (const float*)d_in[7];
  const float* w2  = (const float*)d_in[8];
  const float* bb2 = (const float*)d_in[9];
  const float* g2  = (const float*)d_in[10];
  const float* b2  = (const float*)d_in[11];

  char* ws = (char*)d_ws;
  const size_t MB = 1ull << 20;
  u16* w2T   = (u16*)(ws + 0 * MB);     //  0-8   [prep -> w2]
  u16* hb    = (u16*)(ws + 8 * MB);     //  8-16  [ln1 -> w1, ln2 residual]
  u16* qkP   = (u16*)(ws + 16 * MB);    // 16-48  [qkgemm partials -> khead/attn]
  u16* tbuf  = (u16*)(ws + 16 * MB);    // 16-48  [w1 -> w2]
  u16* obuf  = (u16*)(ws + 48 * MB);    // 48-64  [attn -> combine]
  float* stat = (float*)(ws + 64 * MB); // 64-65  [attn -> combine]
  u16* woP   = (u16*)(ws + 48 * MB);    // 48-80  [wo partials -> ln1]
  u16* rA16  = (u16*)(ws + 48 * MB);    // 48-80  [w2 partials -> ln2]
  u16* xb    = (u16*)(ws + 65 * MB);    // 65-73  [conv -> qkgemm]
  u16* ksum  = (u16*)(ws + 65 * MB);    // 65-73  [khead -> attn]
  u16* kthp  = (u16*)(ws + 73 * MB);    // 73-81  [khead -> attn]
  u16* wqkT  = (u16*)(ws + 81 * MB);    // 81-85  [prep -> qkgemm]
  u16* ctxh  = (u16*)(ws + 81 * MB);    // 81-89  [combine -> wo]
  u16* w1T   = (u16*)(ws + 89 * MB);    // 89-97  [prep -> w1]
  u16* woT   = (u16*)(ws + 97 * MB);    // 97-99  [prep -> wo]

  conv_bf16_kernel<<<1024, 256, 0, stream>>>(x, xb, 1048576);
  transpose_bf16_kernel<1><<<1024, 256, 0, stream>>>(wq, wqkT, 1024, 1024, 0.125f * 1.44269504089f);
  transpose_bf16_kernel<1><<<1024, 256, 0, stream>>>(wk, wqkT + (size_t)1024 * 1024, 1024, 1024, 1.0f);
  transpose_bf16_kernel<2><<<1024, 256, 0, stream>>>(wo, woT, 1024, 1024, 1.0f);
  transpose_bf16_kernel<0><<<32 * 128, 256, 0, stream>>>(w1, w1T, 1024, 4096, 1.0f);
  transpose_bf16_kernel<0><<<128 * 32, 256, 0, stream>>>(w2, w2T, 4096, 1024, 1.0f);

  // q+k projection, split-K=2 (partials summed in consumers)
  gemm256<1, 2><<<256, 512, 0, stream>>>(xb, wqkT, 4096, 2048, 1024, qkP, nullptr);
  khead_transpose<<<1024, 256, 0, stream>>>(qkP, kthp, ksum);

  // attention (V := K per source bug), KV-split=2 + combine
  attn_kernel<<<1024, 256, 0, stream>>>(qkP, ksum, kthp, obuf, stat);
  attn_combine<<<4096, 256, 0, stream>>>(obuf, stat, ctxh);

  // ctx @ wo (split-K=4 partials); ln1 fuses partial-sum + x residual
  gemm256<1, 4><<<256, 512, 0, stream>>>(ctxh, woT, 4096, 1024, 1024, woP, nullptr);
  const size_t MN = (size_t)4096 * 1024;
  ln1_kernel<<<4096, 256, 0, stream>>>(woP, MN, x, g1, b1, hb);

  // FFN
  gemm256<0, 1><<<256, 512, 0, stream>>>(hb, w1T, 4096, 4096, 1024, tbuf, bb1);
  gemm256<1, 4><<<256, 512, 0, stream>>>(tbuf, w2T, 4096, 1024, 4096, rA16, nullptr);
  ln2_kernel<<<4096, 256, 0, stream>>>(rA16, MN, hb, bb2, g2, b2, (float*)d_out);
}

// Round 15
// 235.984 us; speedup vs baseline: 1.1881x; 1.1881x over previous
//
#include <hip/hip_runtime.h>
#include <math.h>

typedef unsigned short u16;
typedef unsigned int u32;
typedef __bf16 bf16x8 __attribute__((ext_vector_type(8)));
typedef unsigned short us8 __attribute__((ext_vector_type(8)));
typedef unsigned short us4 __attribute__((ext_vector_type(4)));
typedef float f32x4 __attribute__((ext_vector_type(4)));

#define DEV __device__ __forceinline__

DEV float fast_exp2(float x) { return __builtin_amdgcn_exp2f(x); }

DEV u16 f2bf(float f) {
  __bf16 h = (__bf16)f;
  return __builtin_bit_cast(u16, h);
}
DEV float bf2f(u16 h) { return __builtin_bit_cast(float, (u32)h << 16); }

DEV bf16x8 ld_bf8(const u16* p) { return __builtin_bit_cast(bf16x8, *(const us8*)p); }

DEV void gload_lds16(const u16* g, u16* l) {
  __builtin_amdgcn_global_load_lds((const __attribute__((address_space(1))) void*)g,
                                   (__attribute__((address_space(3))) void*)l, 16, 0, 0);
}

DEV f32x4 mfma16(bf16x8 a, bf16x8 b, f32x4 c) {
  return __builtin_amdgcn_mfma_f32_16x16x32_bf16(a, b, c, 0, 0, 0);
}

// tanh-form GELU, exp2-based
DEV float fast_gelu(float u) {
  const float e = fast_exp2(-u * (2.3022048f + 0.10294343f * u * u));
  return u / (1.f + e);
}

#define BAR __builtin_amdgcn_s_barrier()
#define LGK asm volatile("s_waitcnt lgkmcnt(0)" ::: "memory")
#define VM4 asm volatile("s_waitcnt vmcnt(4)" ::: "memory")

// ---------------- prep kernels ----------------

__global__ void conv_bf16_kernel(const float* __restrict__ in, u16* __restrict__ out, int n4) {
  const int stride = gridDim.x * blockDim.x;
  for (int i = blockIdx.x * blockDim.x + threadIdx.x; i < n4; i += stride) {
    float4 v = ((const float4*)in)[i];
    us4 h; h[0] = f2bf(v.x); h[1] = f2bf(v.y); h[2] = f2bf(v.z); h[3] = f2bf(v.w);
    ((us4*)out)[i] = h;
  }
}

// in: K x N f32 (row-major) -> out: N x K bf16 (B^T), times scale.
// P=0 plain; P=1 permute OUT row c' = ((c&15)<<6)|(c>>4); P=2 gather IN row src=((r&63)<<4)|(r>>6)
template <int P>
__global__ __launch_bounds__(256) void transpose_bf16_kernel(
    const float* __restrict__ in, u16* __restrict__ out, int K, int N, float scale) {
  __shared__ float tile[32][33];
  const int nbk = K >> 5;
  const int bk = blockIdx.x % nbk, bn = blockIdx.x / nbk;
  const int r0 = bk << 5, c0 = bn << 5;
  const int t = threadIdx.x;
  {
    const int r = t >> 3, c4 = (t & 7) << 2;
    int sr = r0 + r;
    if constexpr (P == 2) sr = ((sr & 63) << 4) | (sr >> 6);
    const float4 v = *(const float4*)(in + (size_t)sr * N + c0 + c4);
    tile[r][c4] = v.x; tile[r][c4 + 1] = v.y; tile[r][c4 + 2] = v.z; tile[r][c4 + 3] = v.w;
  }
  __syncthreads();
  {
    const int oc = t >> 3, r4 = (t & 7) << 2;
    int orow = c0 + oc;
    if constexpr (P == 1) orow = ((orow & 15) << 6) | (orow >> 4);
    us4 h;
#pragma unroll
    for (int j = 0; j < 4; j++) h[j] = f2bf(tile[r4 + j][oc] * scale);
    *(us4*)(out + (size_t)orow * K + r0 + r4) = h;
  }
}

// k half of qkP partials (summed) -> kth [b][n][d][l] and ksum [b][n][l][d]
__global__ __launch_bounds__(256) void khead_transpose(
    const u16* __restrict__ qkP, u16* __restrict__ kth, u16* __restrict__ ksum) {
  __shared__ u16 tT[64 * 64];
  char* base = (char*)tT;
  const size_t PS = (size_t)4096 * 2048;  // partial stride
  const int t = threadIdx.x;
  const int bid = blockIdx.x;
  const int lt = bid & 31, n = (bid >> 5) & 15, b = bid >> 9;
#pragma unroll
  for (int rr = 0; rr < 2; rr++) {
    const int l = rr * 32 + (t >> 3);
    const int d0 = (t & 7) * 8;
    const size_t idx = ((size_t)(b * 2048 + lt * 64 + l)) * 2048 + 1024 + n * 64 + d0;
    us8 va = *(const us8*)(qkP + idx);
    us8 vb = *(const us8*)(qkP + PS + idx);
    us8 sm;
#pragma unroll
    for (int j = 0; j < 8; j++) sm[j] = f2bf(bf2f(va[j]) + bf2f(vb[j]));
    *(us8*)(ksum + (((size_t)(b * 16 + n) * 2048 + lt * 64 + l)) * 64 + d0) = sm;
#pragma unroll
    for (int j = 0; j < 8; j++) {
      const int d = d0 + j;
      *(u16*)(base + d * 128 + ((2 * l) ^ (16 * (d >> 3)))) = sm[j];
    }
  }
  __syncthreads();
  const int w = t >> 6, lane = t & 63;
#pragma unroll
  for (int rr = 0; rr < 2; rr++) {
    const int d = rr * 32 + w * 8 + (lane >> 3);
    const int l = (lane & 7) * 8;
    us8 v = *(const us8*)(base + d * 128 + ((2 * l) ^ (16 * (d >> 3))));
    *(us8*)(kth + ((size_t)((b * 16 + n) * 64 + d)) * 2048 + lt * 64 + l) = v;
  }
}

// ---------------- 4-phase 256x256 GEMM ----------------
// LDS swizzle: seg XOR (row&7) on BOTH stage-source and ds_read (conflict-free).
// 4-phase schedule: 8-phase QUAD pairs merged, halving barriers (8 per 2-K-tiles).
// Each phase: {ds_reads + stage-pair, BAR, 32-MFMA cluster, LGK, [VM4], BAR}.
// vmcnt ledger (verified): F2-end VM4 retires {prev-A1, B1}; F4-end VM4 retires
// {A0, B0}; exactly the next A-pair stays in flight. Scalar-store epilogue is
// deliberate: R14 showed LDS-routed 16B stores cause ~5x HBM write amplification.
// MODE 0: ob = gelu(acc+bias) bf16 ; MODE 1: ob[ks*M*N+.] = acc bf16 partial
template <int MODE, int KS>
__global__ __launch_bounds__(512, 2) void gemm256(
    const u16* __restrict__ A, const u16* __restrict__ BT,
    int M, int N, int K,
    u16* __restrict__ ob, const float* __restrict__ bias) {
  __shared__ u16 AL[2][2][8192];
  __shared__ u16 BL[2][2][8192];
  const int t = threadIdx.x;
  const int lane = t & 63, wid = t >> 6;
  const int lr = lane & 15, lg = lane >> 4;
  const int wm = wid >> 2, wn = wid & 3;
  const int nbm = M >> 8, nbn = N >> 8;
  const int nblk = nbm * nbn * KS;
  int bid = blockIdx.x;
  bid = (bid & 7) * (nblk >> 3) + (bid >> 3);
  int ks = 0;
  if constexpr (KS > 1) { ks = bid % KS; bid /= KS; }
  const int bm = bid % nbm, bn = bid / nbm;
  const int m0 = bm << 8, n0 = bn << 8;
  const int KB = K / KS;
  const int NT = KB >> 6;
  const u16* Ag = A + (size_t)m0 * K + ks * KB;
  const u16* Bg = BT + (size_t)n0 * K + ks * KB;
  const int sseg = (t & 7) ^ ((t >> 3) & 7);
  const int akey = lr & 7;

  auto stgA = [&](int buf, int h, int kt) {
    const u16* s = Ag + (size_t)(h * 128 + (t >> 3)) * K + kt * 64 + sseg * 8;
    gload_lds16(s, &AL[buf][h][t * 8]);
    gload_lds16(s + (size_t)64 * K, &AL[buf][h][4096 + t * 8]);
  };
  auto stgB = [&](int buf, int h, int kt) {
    const u16* s = Bg + (size_t)(h * 128 + (t >> 3)) * K + kt * 64 + sseg * 8;
    gload_lds16(s, &BL[buf][h][t * 8]);
    gload_lds16(s + (size_t)64 * K, &BL[buf][h][4096 + t * 8]);
  };

#define RDA(DST, BUF, IB)                                                      \
  _Pragma("unroll") for (int i4 = 0; i4 < 4; i4++)                             \
  _Pragma("unroll") for (int kk = 0; kk < 2; kk++)                             \
    DST[i4][kk] = ld_bf8(&AL[BUF][wm][((IB + i4) * 16 + lr) * 64 +             \
                                      ((kk * 4 + lg) ^ akey) * 8]);
#define RDB(DST, BUF, JB)                                                      \
  _Pragma("unroll") for (int j2 = 0; j2 < 2; j2++)                             \
  _Pragma("unroll") for (int kk = 0; kk < 2; kk++)                             \
    DST[j2][kk] = ld_bf8(&BL[BUF][wn >> 1][((wn & 1) * 64 + (JB + j2) * 16 +   \
                                            lr) * 64 +                         \
                                           ((kk * 4 + lg) ^ akey) * 8]);
#define QUAD(AF, BF, IB, JB)                                                   \
  __builtin_amdgcn_s_setprio(1);                                               \
  _Pragma("unroll") for (int i4 = 0; i4 < 4; i4++)                             \
  _Pragma("unroll") for (int j2 = 0; j2 < 2; j2++)                             \
  _Pragma("unroll") for (int kk = 0; kk < 2; kk++)                             \
    acc[IB + i4][JB + j2] = mfma16(AF[i4][kk], BF[j2][kk], acc[IB + i4][JB + j2]); \
  __builtin_amdgcn_s_setprio(0);

  f32x4 acc[8][4];
#pragma unroll
  for (int i = 0; i < 8; i++)
#pragma unroll
    for (int j = 0; j < 4; j++) acc[i][j] = (f32x4){0.f, 0.f, 0.f, 0.f};
  bf16x8 a0[4][2], a1[4][2], b0[2][2], b1[2][2];

  stgA(0, 0, 0); stgA(0, 1, 0); stgB(0, 0, 0); stgB(0, 1, 0);
  stgA(1, 0, 1); stgA(1, 1, 1);
  VM4;
  BAR;

  const int NI = NT >> 1;
  for (int it = 0; it < NI; ++it) {
    const int kt1 = 2 * it + 1;
    const int ktA = (2 * it + 2 < NT) ? 2 * it + 2 : NT - 1;
    const int ktB = (2 * it + 3 < NT) ? 2 * it + 3 : NT - 1;
    // F1 (tile X, quadrants 1+2)
    RDA(a0, 0, 0); RDB(b0, 0, 0); RDA(a1, 0, 4); stgB(1, 0, kt1); stgB(1, 1, kt1);
    BAR; QUAD(a0, b0, 0, 0); QUAD(a1, b0, 4, 0); LGK; BAR;
    // F2 (tile X, quadrants 3+4)
    RDB(b1, 0, 2); stgA(0, 0, ktA); stgA(0, 1, ktA);
    BAR; QUAD(a1, b1, 4, 2); QUAD(a0, b1, 0, 2); LGK; VM4; BAR;
    // F3 (tile X+1, quadrants 1+2)
    RDA(a0, 1, 0); RDB(b0, 1, 0); RDA(a1, 1, 4); stgB(0, 0, ktA); stgB(0, 1, ktA);
    BAR; QUAD(a0, b0, 0, 0); QUAD(a1, b0, 4, 0); LGK; BAR;
    // F4 (tile X+1, quadrants 3+4)
    RDB(b1, 1, 2); stgA(1, 0, ktB); stgA(1, 1, ktB);
    BAR; QUAD(a1, b1, 4, 2); QUAD(a0, b1, 0, 2); LGK; VM4; BAR;
  }
#undef RDA
#undef RDB
#undef QUAD

#pragma unroll
  for (int i = 0; i < 8; i++) {
    const int r = m0 + wm * 128 + i * 16 + lg * 4;
#pragma unroll
    for (int j = 0; j < 4; j++) {
      const int c = n0 + wn * 64 + j * 16 + lr;
      if constexpr (MODE == 0) {
        const float bv = bias[c];
#pragma unroll
        for (int q = 0; q < 4; q++)
          ob[(size_t)(r + q) * N + c] = f2bf(fast_gelu(acc[i][j][q] + bv));
      } else {
        u16* op = ob + (size_t)ks * M * N;
#pragma unroll
        for (int q = 0; q < 4; q++) op[(size_t)(r + q) * N + c] = f2bf(acc[i][j][q]);
      }
    }
  }
}

// ---------------- attention (KV-split=2, no-max softmax, MFMA-ones denominator) ----------------
__global__ __launch_bounds__(256, 4) void attn_kernel(
    const u16* __restrict__ qkP, const u16* __restrict__ ksum,
    const u16* __restrict__ kth, u16* __restrict__ op, float* __restrict__ stat) {
  __shared__ u16 KsB[2][4096];
  __shared__ u16 KtsB[2][4096];
  __shared__ u16 Plds[4][1024];
  const size_t PS = (size_t)4096 * 2048;
  const int t = threadIdx.x, w = t >> 6, lane = t & 63;
  const int lr = lane & 15, lg = lane >> 4;
  int bid = blockIdx.x;
  bid = (bid & 7) * 128 + (bid >> 3);
  const int kv = bid & 1, qb = (bid >> 1) & 15, hn = (bid >> 5) & 15, b = bid >> 9;
  const int lw = qb * 128 + w * 32;
  const int m00 = kv * 1024;
  const u16* ksrc = ksum + ((size_t)(b * 16 + hn)) * 2048 * 64;
  const u16* ktb = kth + ((size_t)(b * 16 + hn)) * 64 * 2048;
  char* pb = (char*)&Plds[w][0];
  const int swz = (lr & 7) << 4;

#define STAGE_KV(buf, m0s)                                                    \
  {                                                                           \
    _Pragma("unroll") for (int i_ = 0; i_ < 2; i_++) {                        \
      const int s_ = t + 256 * i_;                                            \
      const int row_ = s_ >> 3;                                               \
      const int c_ = (s_ & 7) ^ (row_ & 7);                                   \
      gload_lds16(ksrc + (size_t)((m0s) + row_) * 64 + c_ * 8,                \
                  &KsB[buf][s_ * 8]);                                         \
      gload_lds16(ktb + (size_t)row_ * 2048 + (m0s) + c_ * 8,                 \
                  &KtsB[buf][s_ * 8]);                                        \
    }                                                                         \
  }

  bf16x8 qf[2][2];
#pragma unroll
  for (int f = 0; f < 2; f++)
#pragma unroll
    for (int kk = 0; kk < 2; kk++) {
      const size_t qi = (size_t)(b * 2048 + lw + 16 * f + lr) * 2048 + hn * 64 +
                        kk * 32 + lg * 8;
      us8 qa = *(const us8*)(qkP + qi);
      us8 qb2 = *(const us8*)(qkP + PS + qi);
      us8 qs;
#pragma unroll
      for (int j = 0; j < 8; j++) qs[j] = f2bf(bf2f(qa[j]) + bf2f(qb2[j]));
      qf[f][kk] = __builtin_bit_cast(bf16x8, qs);
    }

  us8 ou;
#pragma unroll
  for (int j = 0; j < 8; j++) ou[j] = 0x3f80;  // bf16 1.0
  const bf16x8 ones = __builtin_bit_cast(bf16x8, ou);

  f32x4 ol[2];
  f32x4 o[2][4];
#pragma unroll
  for (int f = 0; f < 2; f++) {
    ol[f] = (f32x4){0.f, 0.f, 0.f, 0.f};
#pragma unroll
    for (int dj = 0; dj < 4; dj++) o[f][dj] = (f32x4){0.f, 0.f, 0.f, 0.f};
  }

  STAGE_KV(0, m00);
  __syncthreads();

  for (int it = 0; it < 16; ++it) {
    const int buf = it & 1;
    if (it < 15) STAGE_KV(buf ^ 1, m00 + (it + 1) * 64);

    f32x4 sc[2][4];
#pragma unroll
    for (int f = 0; f < 2; f++)
#pragma unroll
      for (int mj = 0; mj < 4; mj++) sc[f][mj] = (f32x4){0.f, 0.f, 0.f, 0.f};
    __builtin_amdgcn_s_setprio(1);
#pragma unroll
    for (int mj = 0; mj < 4; mj++) {
      const int krow = 16 * mj + lr;
      bf16x8 kf0 = ld_bf8(&KsB[buf][krow * 64 + ((lg ^ (krow & 7)) << 3)]);
      bf16x8 kf1 = ld_bf8(&KsB[buf][krow * 64 + (((4 + lg) ^ (krow & 7)) << 3)]);
#pragma unroll
      for (int f = 0; f < 2; f++) {
        sc[f][mj] = mfma16(kf0, qf[f][0], sc[f][mj]);
        sc[f][mj] = mfma16(kf1, qf[f][1], sc[f][mj]);
      }
    }
    __builtin_amdgcn_s_setprio(0);

    bf16x8 pa[2][2];
#pragma unroll
    for (int f = 0; f < 2; f++) {
#pragma unroll
      for (int mj = 0; mj < 4; mj++) {
        float p0 = fast_exp2(sc[f][mj][0]);
        float p1 = fast_exp2(sc[f][mj][1]);
        float p2 = fast_exp2(sc[f][mj][2]);
        float p3 = fast_exp2(sc[f][mj][3]);
        u32 w0 = (u32)f2bf(p0) | ((u32)f2bf(p1) << 16);
        u32 w1 = (u32)f2bf(p2) | ((u32)f2bf(p3) << 16);
        *(uint2*)(pb + ((lr * 128 + mj * 32 + lg * 8) ^ swz)) = make_uint2(w0, w1);
      }
#pragma unroll
      for (int kk = 0; kk < 2; kk++)
        pa[f][kk] = __builtin_bit_cast(
            bf16x8, *(const us8*)(pb + ((lr * 128 + kk * 64 + lg * 16) ^ swz)));
      ol[f] = mfma16(pa[f][0], ones, ol[f]);
      ol[f] = mfma16(pa[f][1], ones, ol[f]);
    }

    __builtin_amdgcn_s_setprio(1);
#pragma unroll
    for (int dj = 0; dj < 4; dj++) {
      const int vrow = dj * 16 + lr;
      bf16x8 v0 = ld_bf8(&KtsB[buf][vrow * 64 + ((lg ^ (vrow & 7)) << 3)]);
      bf16x8 v1 = ld_bf8(&KtsB[buf][vrow * 64 + (((4 + lg) ^ (vrow & 7)) << 3)]);
#pragma unroll
      for (int f = 0; f < 2; f++) {
        o[f][dj] = mfma16(pa[f][0], v0, o[f][dj]);
        o[f][dj] = mfma16(pa[f][1], v1, o[f][dj]);
      }
    }
    __builtin_amdgcn_s_setprio(0);
    __syncthreads();
  }
#undef STAGE_KV

  u16* ob = op + (size_t)kv * 4096 * 1024;
#pragma unroll
  for (int f = 0; f < 2; f++) {
#pragma unroll
    for (int q = 0; q < 4; q++) {
      const int ll = lw + 16 * f + 4 * lg + q;
#pragma unroll
      for (int dj = 0; dj < 4; dj++) {
        ob[((size_t)(b * 2048 + ll)) * 1024 + hn * 64 + dj * 16 + lr] = f2bf(o[f][dj][q]);
      }
    }
    if (lr == 0) {
      const int sb = (b * 16 + hn) * 2048 + lw + 16 * f + 4 * lg;
#pragma unroll
      for (int q = 0; q < 4; q++) stat[kv * 65536 + sb + q] = ol[f][q];
    }
  }
}

// combine: ctx = (o0 + o1) / (l0 + l1)
__global__ __launch_bounds__(256) void attn_combine(
    const u16* __restrict__ op, const float* __restrict__ stat, u16* __restrict__ ctxh) {
  const int row = blockIdx.x, t = threadIdx.x;
  const int hn = t >> 4;
  const int b = row >> 11, l = row & 2047;
  const int sidx = (b * 16 + hn) * 2048 + l;
  const float inv = 1.f / (stat[sidx] + stat[65536 + sidx]);
  const us4 a = *(const us4*)(op + (size_t)row * 1024 + t * 4);
  const us4 c = *(const us4*)(op + (size_t)(4096 + row) * 1024 + t * 4);
  us4 h;
#pragma unroll
  for (int j = 0; j < 4; j++) h[j] = f2bf((bf2f(a[j]) + bf2f(c[j])) * inv);
  *(us4*)(ctxh + (size_t)row * 1024 + t * 4) = h;
}

// ---------------- layernorm ----------------
// ln1: 4 bf16 wo-partials + f32 x residual -> LN -> bf16 out
__global__ __launch_bounds__(256) void ln1_kernel(
    const u16* __restrict__ p, size_t pstride, const float* __restrict__ xres,
    const float* __restrict__ gamma, const float* __restrict__ beta,
    u16* __restrict__ o16) {
  __shared__ float red[8];
  const int row = blockIdx.x, t = threadIdx.x;
  float4 v = ((const float4*)(xres + (size_t)row * 1024))[t];
#pragma unroll
  for (int k = 0; k < 4; k++) {
    const us4 pv = *(const us4*)(p + (size_t)k * pstride + (size_t)row * 1024 + t * 4);
    v.x += bf2f(pv[0]); v.y += bf2f(pv[1]); v.z += bf2f(pv[2]); v.w += bf2f(pv[3]);
  }
  float s = v.x + v.y + v.z + v.w;
  float ss = v.x * v.x + v.y * v.y + v.z * v.z + v.w * v.w;
#pragma unroll
  for (int off = 1; off < 64; off <<= 1) { s += __shfl_xor(s, off); ss += __shfl_xor(ss, off); }
  if ((t & 63) == 0) { red[t >> 6] = s; red[4 + (t >> 6)] = ss; }
  __syncthreads();
  const float st = red[0] + red[1] + red[2] + red[3];
  const float sst = red[4] + red[5] + red[6] + red[7];
  const float mean = st * (1.f / 1024.f);
  const float var = sst * (1.f / 1024.f) - mean * mean;
  const float rs = rsqrtf(var + 1e-5f);
  const float4 gv = ((const float4*)gamma)[t];
  const float4 bv = ((const float4*)beta)[t];
  us4 h;
  h[0] = f2bf((v.x - mean) * rs * gv.x + bv.x);
  h[1] = f2bf((v.y - mean) * rs * gv.y + bv.y);
  h[2] = f2bf((v.z - mean) * rs * gv.z + bv.z);
  h[3] = f2bf((v.w - mean) * rs * gv.w + bv.w);
  *(us4*)(o16 + (size_t)row * 1024 + t * 4) = h;
}

// ln2: 4 bf16 partials + bf16 residual + bias -> LN -> f32 out
__global__ __launch_bounds__(256) void ln2_kernel(
    const u16* __restrict__ p, size_t pstride,
    const u16* __restrict__ resb, const float* __restrict__ bias,
    const float* __restrict__ gamma, const float* __restrict__ beta,
    float* __restrict__ o32) {
  __shared__ float red[8];
  const int row = blockIdx.x, t = threadIdx.x;
  float4 v;
  {
    const float4 vb = ((const float4*)bias)[t];
    const us4 rb = *(const us4*)(resb + (size_t)row * 1024 + t * 4);
    v.x = bf2f(rb[0]) + vb.x;
    v.y = bf2f(rb[1]) + vb.y;
    v.z = bf2f(rb[2]) + vb.z;
    v.w = bf2f(rb[3]) + vb.w;
  }
#pragma unroll
  for (int k = 0; k < 4; k++) {
    const us4 pv = *(const us4*)(p + (size_t)k * pstride + (size_t)row * 1024 + t * 4);
    v.x += bf2f(pv[0]); v.y += bf2f(pv[1]); v.z += bf2f(pv[2]); v.w += bf2f(pv[3]);
  }
  float s = v.x + v.y + v.z + v.w;
  float ss = v.x * v.x + v.y * v.y + v.z * v.z + v.w * v.w;
#pragma unroll
  for (int off = 1; off < 64; off <<= 1) { s += __shfl_xor(s, off); ss += __shfl_xor(ss, off); }
  if ((t & 63) == 0) { red[t >> 6] = s; red[4 + (t >> 6)] = ss; }
  __syncthreads();
  const float st = red[0] + red[1] + red[2] + red[3];
  const float sst = red[4] + red[5] + red[6] + red[7];
  const float mean = st * (1.f / 1024.f);
  const float var = sst * (1.f / 1024.f) - mean * mean;
  const float rs = rsqrtf(var + 1e-5f);
  const float4 gv = ((const float4*)gamma)[t];
  const float4 bv = ((const float4*)beta)[t];
  float4 ov;
  ov.x = (v.x - mean) * rs * gv.x + bv.x;
  ov.y = (v.y - mean) * rs * gv.y + bv.y;
  ov.z = (v.z - mean) * rs * gv.z + bv.z;
  ov.w = (v.w - mean) * rs * gv.w + bv.w;
  ((float4*)(o32 + (size_t)row * 1024))[t] = ov;
}

// ---------------- launch ----------------
extern "C" void kernel_launch(void* const* d_in, const int* in_sizes, int n_in,
                              void* d_out, int out_size, void* d_ws, size_t ws_size,
                              hipStream_t stream) {
  const float* x   = (const float*)d_in[0];
  const float* wq  = (const float*)d_in[1];
  const float* wk  = (const float*)d_in[2];
  const float* wo  = (const float*)d_in[3];
  const float* g1  = (const float*)d_in[4];
  const float* b1  = (const float*)d_in[5];
  const float* w1  = (const float*)d_in[6];
  const float* bb1 = (const float*)d_in[7];
  const float* w2  = (const float*)d_in[8];
  const float* bb2 = (const float*)d_in[9];
  const float* g2  = (const float*)d_in[10];
  const float* b2  = (const float*)d_in[11];

  char* ws = (char*)d_ws;
  const size_t MB = 1ull << 20;
  u16* w2T   = (u16*)(ws + 0 * MB);     //  0-8   [prep -> w2]
  u16* hb    = (u16*)(ws + 8 * MB);     //  8-16  [ln1 -> w1, ln2 residual]
  u16* qkP   = (u16*)(ws + 16 * MB);    // 16-48  [qkgemm partials -> khead/attn]
  u16* tbuf  = (u16*)(ws + 16 * MB);    // 16-48  [w1 -> w2]
  u16* obuf  = (u16*)(ws + 48 * MB);    // 48-64  [attn -> combine]
  float* stat = (float*)(ws + 64 * MB); // 64-65  [attn -> combine]
  u16* woP   = (u16*)(ws + 48 * MB);    // 48-80  [wo partials -> ln1]
  u16* rA16  = (u16*)(ws + 48 * MB);    // 48-80  [w2 partials -> ln2]
  u16* xb    = (u16*)(ws + 65 * MB);    // 65-73  [conv -> qkgemm]
  u16* ksum  = (u16*)(ws + 65 * MB);    // 65-73  [khead -> attn]
  u16* kthp  = (u16*)(ws + 73 * MB);    // 73-81  [khead -> attn]
  u16* wqkT  = (u16*)(ws + 81 * MB);    // 81-85  [prep -> qkgemm]
  u16* ctxh  = (u16*)(ws + 81 * MB);    // 81-89  [combine -> wo]
  u16* w1T   = (u16*)(ws + 89 * MB);    // 89-97  [prep -> w1]
  u16* woT   = (u16*)(ws + 97 * MB);    // 97-99  [prep -> wo]

  conv_bf16_kernel<<<1024, 256, 0, stream>>>(x, xb, 1048576);
  transpose_bf16_kernel<1><<<1024, 256, 0, stream>>>(wq, wqkT, 1024, 1024, 0.125f * 1.44269504089f);
  transpose_bf16_kernel<1><<<1024, 256, 0, stream>>>(wk, wqkT + (size_t)1024 * 1024, 1024, 1024, 1.0f);
  transpose_bf16_kernel<2><<<1024, 256, 0, stream>>>(wo, woT, 1024, 1024, 1.0f);
  transpose_bf16_kernel<0><<<32 * 128, 256, 0, stream>>>(w1, w1T, 1024, 4096, 1.0f);
  transpose_bf16_kernel<0><<<128 * 32, 256, 0, stream>>>(w2, w2T, 4096, 1024, 1.0f);

  // q+k projection, split-K=2 (partials summed in consumers)
  gemm256<1, 2><<<256, 512, 0, stream>>>(xb, wqkT, 4096, 2048, 1024, qkP, nullptr);
  khead_transpose<<<1024, 256, 0, stream>>>(qkP, kthp, ksum);

  // attention (V := K per source bug), KV-split=2 + combine
  attn_kernel<<<1024, 256, 0, stream>>>(qkP, ksum, kthp, obuf, stat);
  attn_combine<<<4096, 256, 0, stream>>>(obuf, stat, ctxh);

  // ctx @ wo (split-K=4 partials); ln1 fuses partial-sum + x residual
  gemm256<1, 4><<<256, 512, 0, stream>>>(ctxh, woT, 4096, 1024, 1024, woP, nullptr);
  const size_t MN = (size_t)4096 * 1024;
  ln1_kernel<<<4096, 256, 0, stream>>>(woP, MN, x, g1, b1, hb);

  // FFN
  gemm256<0, 1><<<256, 512, 0, stream>>>(hb, w1T, 4096, 4096, 1024, tbuf, bb1);
  gemm256<1, 4><<<256, 512, 0, stream>>>(tbuf, w2T, 4096, 1024, 4096, rA16, nullptr);
  ln2_kernel<<<4096, 256, 0, stream>>>(rA16, MN, hb, bb2, g2, b2, (float*)d_out);
}